// Round 3
// baseline (440.768 us; speedup 1.0000x reference)
//
#include <hip/hip_runtime.h>

// toy_gnn scatter-add: out[dst[e], f] += w_mp * edge_weight[e] * x[src[e], f]
// N=100000, E=1600000, F=32, fp32.
//
// Round 2 -> 3: R2's scatter_pairs wrote 100 MB HBM (1.6M random 8B stores x
// 64B sector write-through). Replace fine CSR sort with coarse 256-node
// buckets: block-batched binning (dense per-bucket runs, 4B records) +
// per-bucket LDS-tile aggregation with ds_add_f32 (zero global atomics,
// only coalesced output stores).

constexpr int N_NODES = 100000;
constexpr int N_EDGES = 1600000;
constexpr int F_DIM   = 32;

constexpr int NPB  = 256;                          // nodes per bucket
constexpr int NB   = (N_NODES + NPB - 1) / NPB;    // 391 buckets
constexpr int CAP  = 4608;                         // records per bucket (mean 4096 + 8 sigma)
constexpr int CHUNK = 4096;                        // edges per bin block
constexpr int EPT   = CHUNK / 256;                 // 16 edges per thread
constexpr int NBIN_BLOCKS = (N_EDGES + CHUNK - 1) / CHUNK;  // 391

// ---------------- workspace layout ----------------
// [0)            gcursor : NB ints
// [2048)         records : NB*CAP uints  (~7.2 MB)
constexpr size_t WS_CURSOR  = 0;
constexpr size_t WS_RECORDS = 2048;
constexpr size_t WS_NEEDED  = WS_RECORDS + (size_t)NB * CAP * 4;

__global__ __launch_bounds__(256) void init_cursors(int* __restrict__ gcursor)
{
    int i = blockIdx.x * 256 + threadIdx.x;
    if (i < NB) gcursor[i] = i * CAP;
}

__global__ __launch_bounds__(256) void bin_edges(
    const int* __restrict__ dst,
    int* __restrict__ gcursor,
    unsigned* __restrict__ records)
{
    __shared__ int lhist[NB];
    __shared__ int lbase[NB];
    for (int i = threadIdx.x; i < NB; i += 256) lhist[i] = 0;
    __syncthreads();

    const int base_e = blockIdx.x * CHUNK;
    int      bkt[EPT];
    unsigned rec[EPT];

    #pragma unroll
    for (int i = 0; i < EPT; ++i) {
        int e = base_e + threadIdx.x + i * 256;
        int b = -1;
        unsigned r = 0;
        if (e < N_EDGES) {
            int d = dst[e];
            b = d >> 8;
            r = (unsigned)e | ((unsigned)(d & 255) << 21);  // e < 2^21
            atomicAdd(&lhist[b], 1);
        }
        bkt[i] = b;
        rec[i] = r;
    }
    __syncthreads();

    for (int i = threadIdx.x; i < NB; i += 256) {
        int c = lhist[i];
        lbase[i] = c ? atomicAdd(&gcursor[i], c) : 0;
        lhist[i] = 0;
    }
    __syncthreads();

    #pragma unroll
    for (int i = 0; i < EPT; ++i) {
        int b = bkt[i];
        if (b >= 0) {
            int slot = atomicAdd(&lhist[b], 1);
            int pos  = lbase[b] + slot;
            if (pos < (b + 1) * CAP)          // overflow guard (never hits at 8 sigma)
                records[pos] = rec[i];
        }
    }
}

__global__ __launch_bounds__(512) void aggregate(
    const int*      __restrict__ src,
    const float*    __restrict__ ew,
    const float*    __restrict__ w_mp,
    const float*    __restrict__ x,
    const int*      __restrict__ gcursor,
    const unsigned* __restrict__ records,
    float*          __restrict__ out)
{
    __shared__ float tile[NPB * F_DIM];   // 32 KB
    const int b = blockIdx.x;

    // zero tile
    float4* t4 = reinterpret_cast<float4*>(tile);
    for (int i = threadIdx.x; i < NPB * F_DIM / 4; i += 512)
        t4[i] = make_float4(0.f, 0.f, 0.f, 0.f);
    __syncthreads();

    const float w    = w_mp[0];
    const int  cnt   = min(gcursor[b] - b * CAP, CAP);
    const int  rbase = b * CAP;
    const int  g     = threadIdx.x >> 3;        // edge slot within batch of 64
    const int  q     = (threadIdx.x & 7) * 4;   // float4 slice of the row

    for (int j = g; j < cnt; j += 64) {
        unsigned r = records[rbase + j];
        int e = r & 0x1FFFFF;
        if (e < N_EDGES) {                      // guards poison if overflow dropped
            int   dl = (r >> 21) & 0xFF;
            float c  = w * ew[e];
            int   s  = src[e];
            const float4 xv = *reinterpret_cast<const float4*>(
                x + (size_t)s * F_DIM + q);
            int rowbase = dl << 5;              // dl * 32
            // column rotation by dl: breaks 8-way bank aliasing to ~2-way
            __hip_atomic_fetch_add(&tile[rowbase + ((q + 0 + dl) & 31)], c * xv.x,
                                   __ATOMIC_RELAXED, __HIP_MEMORY_SCOPE_WORKGROUP);
            __hip_atomic_fetch_add(&tile[rowbase + ((q + 1 + dl) & 31)], c * xv.y,
                                   __ATOMIC_RELAXED, __HIP_MEMORY_SCOPE_WORKGROUP);
            __hip_atomic_fetch_add(&tile[rowbase + ((q + 2 + dl) & 31)], c * xv.z,
                                   __ATOMIC_RELAXED, __HIP_MEMORY_SCOPE_WORKGROUP);
            __hip_atomic_fetch_add(&tile[rowbase + ((q + 3 + dl) & 31)], c * xv.w,
                                   __ATOMIC_RELAXED, __HIP_MEMORY_SCOPE_WORKGROUP);
        }
    }
    __syncthreads();

    // flush (un-rotate): out[n*32 + col] = tile[r*32 + (col+r)&31]
    const int nb0 = b * NPB;
    for (int i = threadIdx.x; i < NPB * F_DIM; i += 512) {
        int rr  = i >> 5;
        int col = i & 31;
        int n   = nb0 + rr;
        if (n < N_NODES)
            out[(size_t)n * F_DIM + col] = tile[(rr << 5) + ((col + rr) & 31)];
    }
}

// ---------------- fallback (R0): plain atomic scatter ----------------
__global__ __launch_bounds__(256) void gnn_scatter_atomic(
    const float* __restrict__ x, const int* __restrict__ src,
    const int* __restrict__ dst, const float* __restrict__ ew,
    const float* __restrict__ w_mp, float* __restrict__ out)
{
    const float w = w_mp[0];
    int gid = blockIdx.x * blockDim.x + threadIdx.x;
    int e = gid >> 3;
    int qq = (gid & 7) * 4;
    if (e >= N_EDGES) return;
    int s = src[e];
    int d = dst[e];
    float c = w * ew[e];
    const float4 xv = *reinterpret_cast<const float4*>(x + (size_t)s * F_DIM + qq);
    float* op = out + (size_t)d * F_DIM + qq;
    atomicAdd(op + 0, c * xv.x);
    atomicAdd(op + 1, c * xv.y);
    atomicAdd(op + 2, c * xv.z);
    atomicAdd(op + 3, c * xv.w);
}

extern "C" void kernel_launch(void* const* d_in, const int* in_sizes, int n_in,
                              void* d_out, int out_size, void* d_ws, size_t ws_size,
                              hipStream_t stream) {
    const float* x    = (const float*)d_in[0];
    const int*   ei   = (const int*)d_in[1];   // [2, E]: src row, then dst row
    const float* ew   = (const float*)d_in[2];
    const float* w_mp = (const float*)d_in[3];
    float* out = (float*)d_out;

    const int* src = ei;
    const int* dst = ei + N_EDGES;

    if (ws_size < WS_NEEDED) {
        hipMemsetAsync(d_out, 0, (size_t)out_size * sizeof(float), stream);
        int total = N_EDGES * 8;
        gnn_scatter_atomic<<<(total + 255) / 256, 256, 0, stream>>>(
            x, src, dst, ew, w_mp, out);
        return;
    }

    char* ws = (char*)d_ws;
    int*      gcursor = (int*)(ws + WS_CURSOR);
    unsigned* records = (unsigned*)(ws + WS_RECORDS);

    init_cursors<<<(NB + 255) / 256, 256, 0, stream>>>(gcursor);
    bin_edges<<<NBIN_BLOCKS, 256, 0, stream>>>(dst, gcursor, records);
    aggregate<<<NB, 512, 0, stream>>>(src, ew, w_mp, x, gcursor, records, out);
    // aggregate writes every out element -> no d_out memset needed
}

// Round 4
// 142.372 us; speedup vs baseline: 3.0959x; 3.0959x over previous
//
#include <hip/hip_runtime.h>

// toy_gnn scatter-add: out[dst[e], f] += w_mp * edge_weight[e] * x[src[e], f]
// N=100000, E=1600000, F=32, fp32.
//
// Round 4: exact CSR via two-stage counting sort + atomic-free per-node gather.
//   R3 lesson: the x-gather is latency-bound -> needs >=2000 blocks and a
//   2-deep load chain. R3's aggregate had 391 blocks (occ 26.7%, 0.61 TB/s).
//   Pipeline: coarse-bin dense 8B records (coef,src,dl) -> per-bucket LDS
//   counting sort (in-place, coalesced) -> per-node gather (3125 blocks,
//   coef embedded, zero atomics, one 128B store per node).

constexpr int N_NODES = 100000;
constexpr int N_EDGES = 1600000;
constexpr int F_DIM   = 32;

constexpr int NPB = 256;                          // nodes per bucket
constexpr int NB  = (N_NODES + NPB - 1) / NPB;    // 391 buckets
constexpr int CAP = 4608;                         // bucket capacity (mean 4096 + 8 sigma)

constexpr int BIN_THREADS = 512;
constexpr int BIN_EPT     = 16;
constexpr int BIN_CHUNK   = BIN_THREADS * BIN_EPT;              // 8192
constexpr int BIN_BLOCKS  = (N_EDGES + BIN_CHUNK - 1) / BIN_CHUNK;  // 196

constexpr int SORT_THREADS = 512;
constexpr int RPT = (CAP + SORT_THREADS - 1) / SORT_THREADS;    // 9

// ---------------- workspace layout (bytes) ----------------
constexpr size_t WS_CURSOR  = 0;                      // NB ints
constexpr size_t WS_BEGIN   = 4096;                   // N ints
constexpr size_t WS_END     = WS_BEGIN + 400000;      // N ints
constexpr size_t WS_RECORDS = WS_END + 400000;        // NB*CAP uint2 (8B)
constexpr size_t WS_NEEDED  = WS_RECORDS + (size_t)NB * CAP * 8;  // ~15.2 MB

__global__ __launch_bounds__(256) void init_cursors(int* __restrict__ gcursor)
{
    int i = blockIdx.x * 256 + threadIdx.x;
    if (i < NB) gcursor[i] = i * CAP;
}

__global__ __launch_bounds__(BIN_THREADS) void bin_edges(
    const int* __restrict__ src, const int* __restrict__ dst,
    const float* __restrict__ ew, const float* __restrict__ w_mp,
    int* __restrict__ gcursor, uint2* __restrict__ records)
{
    __shared__ int lhist[NB];
    __shared__ int lbase[NB];
    for (int i = threadIdx.x; i < NB; i += BIN_THREADS) lhist[i] = 0;
    __syncthreads();

    const float w = w_mp[0];
    const int base_e = blockIdx.x * BIN_CHUNK;
    int   bkt[BIN_EPT];
    uint2 rec[BIN_EPT];

    #pragma unroll
    for (int i = 0; i < BIN_EPT; ++i) {
        int e = base_e + threadIdx.x + i * BIN_THREADS;
        bkt[i] = -1;
        if (e < N_EDGES) {
            int d = dst[e];
            int b = d >> 8;
            bkt[i] = b;
            rec[i].x = __float_as_uint(w * ew[e]);
            rec[i].y = (unsigned)src[e] | ((unsigned)(d & 255) << 24);
            atomicAdd(&lhist[b], 1);
        }
    }
    __syncthreads();

    for (int i = threadIdx.x; i < NB; i += BIN_THREADS) {
        int c = lhist[i];
        lbase[i] = c ? atomicAdd(&gcursor[i], c) : 0;
        lhist[i] = 0;
    }
    __syncthreads();

    #pragma unroll
    for (int i = 0; i < BIN_EPT; ++i) {
        int b = bkt[i];
        if (b >= 0) {
            int pos = lbase[b] + atomicAdd(&lhist[b], 1);
            if (pos < (b + 1) * CAP)            // overflow guard (8-sigma margin)
                records[pos] = rec[i];
        }
    }
}

__global__ __launch_bounds__(SORT_THREADS) void bucket_sort(
    const int* __restrict__ gcursor, uint2* __restrict__ records,
    int* __restrict__ begin, int* __restrict__ end)
{
    __shared__ uint2 sorted[CAP];        // 36864 B
    __shared__ int   scan[NPB + 1];      // inclusive scan, scan[0]=0
    __shared__ int   cursor[NPB];

    const int b     = blockIdx.x;
    const int t     = threadIdx.x;
    const int rbase = b * CAP;
    int cnt = min(gcursor[b] - rbase, CAP);

    if (t <= NPB) scan[t] = 0;
    if (t < NPB)  cursor[t] = 0;
    __syncthreads();

    // load this bucket's records into registers + LDS histogram by dst_low
    uint2 rec[RPT];
    bool  have[RPT];
    #pragma unroll
    for (int i = 0; i < RPT; ++i) {
        int j = t + i * SORT_THREADS;
        have[i] = (j < cnt);
        if (have[i]) {
            rec[i] = records[rbase + j];
            atomicAdd(&cursor[rec[i].y >> 24], 1);
        }
    }
    __syncthreads();

    if (t < NPB) scan[t + 1] = cursor[t];
    __syncthreads();
    // Hillis-Steele inclusive scan over scan[1..256]
    for (int d = 1; d < NPB; d <<= 1) {
        int v = 0;
        if (t >= 1 && t <= NPB) v = (t > d) ? scan[t - d] : 0;
        __syncthreads();
        if (t >= 1 && t <= NPB) scan[t] += v;
        __syncthreads();
    }
    if (t < NPB) cursor[t] = scan[t];    // exclusive offsets as placement cursors
    __syncthreads();

    // place into LDS in dst order
    #pragma unroll
    for (int i = 0; i < RPT; ++i) {
        if (have[i]) {
            int slot = atomicAdd(&cursor[rec[i].y >> 24], 1);
            sorted[slot] = rec[i];
        }
    }
    __syncthreads();

    // write back in-place (coalesced), bucket region is private to this block
    #pragma unroll
    for (int i = 0; i < RPT; ++i) {
        int j = t + i * SORT_THREADS;
        if (j < cnt) records[rbase + j] = sorted[j];
    }

    // per-node ranges
    int node0 = b * NPB;
    if (t < NPB && node0 + t < N_NODES) {
        begin[node0 + t] = rbase + scan[t];
        end[node0 + t]   = rbase + scan[t + 1];
    }
}

__global__ __launch_bounds__(256) void gather(
    const int* __restrict__ begin, const int* __restrict__ end,
    const uint2* __restrict__ records, const float* __restrict__ x,
    float* __restrict__ out)
{
    int gid  = blockIdx.x * 256 + threadIdx.x;
    int node = gid >> 3;           // 8 threads per node
    int q    = (gid & 7) * 4;      // float4 slice of the 32-float row
    if (node >= N_NODES) return;

    int j  = begin[node];
    int je = end[node];
    float4 acc = make_float4(0.f, 0.f, 0.f, 0.f);
    for (; j < je; ++j) {
        uint2 r = records[j];
        float c = __uint_as_float(r.x);
        int   s = r.y & 0xFFFFFF;
        const float4 xv = *reinterpret_cast<const float4*>(
            x + (size_t)s * F_DIM + q);
        acc.x += c * xv.x;
        acc.y += c * xv.y;
        acc.z += c * xv.z;
        acc.w += c * xv.w;
    }
    *reinterpret_cast<float4*>(out + (size_t)node * F_DIM + q) = acc;
}

// ---------------- fallback (R0): plain atomic scatter ----------------
__global__ __launch_bounds__(256) void gnn_scatter_atomic(
    const float* __restrict__ x, const int* __restrict__ src,
    const int* __restrict__ dst, const float* __restrict__ ew,
    const float* __restrict__ w_mp, float* __restrict__ out)
{
    const float w = w_mp[0];
    int gid = blockIdx.x * blockDim.x + threadIdx.x;
    int e = gid >> 3;
    int qq = (gid & 7) * 4;
    if (e >= N_EDGES) return;
    int s = src[e];
    int d = dst[e];
    float c = w * ew[e];
    const float4 xv = *reinterpret_cast<const float4*>(x + (size_t)s * F_DIM + qq);
    float* op = out + (size_t)d * F_DIM + qq;
    atomicAdd(op + 0, c * xv.x);
    atomicAdd(op + 1, c * xv.y);
    atomicAdd(op + 2, c * xv.z);
    atomicAdd(op + 3, c * xv.w);
}

extern "C" void kernel_launch(void* const* d_in, const int* in_sizes, int n_in,
                              void* d_out, int out_size, void* d_ws, size_t ws_size,
                              hipStream_t stream) {
    const float* x    = (const float*)d_in[0];
    const int*   ei   = (const int*)d_in[1];   // [2, E]: src row, then dst row
    const float* ew   = (const float*)d_in[2];
    const float* w_mp = (const float*)d_in[3];
    float* out = (float*)d_out;

    const int* src = ei;
    const int* dst = ei + N_EDGES;

    if (ws_size < WS_NEEDED) {
        hipMemsetAsync(d_out, 0, (size_t)out_size * sizeof(float), stream);
        int total = N_EDGES * 8;
        gnn_scatter_atomic<<<(total + 255) / 256, 256, 0, stream>>>(
            x, src, dst, ew, w_mp, out);
        return;
    }

    char* ws = (char*)d_ws;
    int*   gcursor = (int*)(ws + WS_CURSOR);
    int*   begin   = (int*)(ws + WS_BEGIN);
    int*   end     = (int*)(ws + WS_END);
    uint2* records = (uint2*)(ws + WS_RECORDS);

    init_cursors<<<(NB + 255) / 256, 256, 0, stream>>>(gcursor);
    bin_edges<<<BIN_BLOCKS, BIN_THREADS, 0, stream>>>(src, dst, ew, w_mp,
                                                      gcursor, records);
    bucket_sort<<<NB, SORT_THREADS, 0, stream>>>(gcursor, records, begin, end);

    int gthreads = N_NODES * 8;
    gather<<<(gthreads + 255) / 256, 256, 0, stream>>>(begin, end, records, x, out);
    // gather writes every out element -> no d_out memset needed
}

// Round 5
// 135.902 us; speedup vs baseline: 3.2433x; 1.0476x over previous
//
#include <hip/hip_runtime.h>

// toy_gnn scatter-add: out[dst[e], f] += w_mp * edge_weight[e] * x[src[e], f]
// N=100000, E=1600000, F=32, fp32.
//
// Round 5: fused bucket-sort + gather, 64-node buckets (NB=1563 blocks).
//   R4 lesson: bucket_sort round-tripped 12.8 MB records through global and
//   ran at 391 blocks (under-occupied); gather's 2-deep dependent chain had
//   1 outstanding x-load/thread. Now: bin dense 8B records into 1563 bucket
//   regions -> one kernel per bucket counting-sorts in LDS (wave-shuffle
//   scan) and gathers straight from LDS with a 4-way unrolled x-load loop.
//   Zero fp32 atomics; only coalesced 128B/node output stores.

constexpr int N_NODES = 100000;
constexpr int N_EDGES = 1600000;
constexpr int F_DIM   = 32;

constexpr int NPB = 64;                            // nodes per bucket
constexpr int NB  = (N_NODES + NPB - 1) / NPB;     // 1563 buckets
constexpr int CAP = 1344;                          // mean 1024 + 10 sigma(32)

constexpr int BIN_THREADS = 512;
constexpr int BIN_EPT     = 8;
constexpr int BIN_CHUNK   = BIN_THREADS * BIN_EPT;                  // 4096
constexpr int BIN_BLOCKS  = (N_EDGES + BIN_CHUNK - 1) / BIN_CHUNK;  // 391

constexpr int AGG_THREADS = 512;                   // 8 waves; 8 thr/node x 64 nodes
constexpr int RPT = (CAP + AGG_THREADS - 1) / AGG_THREADS;          // 3

// ---------------- workspace layout (bytes) ----------------
constexpr size_t WS_CURSOR  = 0;                   // NB ints
constexpr size_t WS_RECORDS = 8192;                // NB*CAP uint2
constexpr size_t WS_NEEDED  = WS_RECORDS + (size_t)NB * CAP * 8;  // ~16.8 MB

__global__ __launch_bounds__(256) void init_cursors(int* __restrict__ gcursor)
{
    int i = blockIdx.x * 256 + threadIdx.x;
    if (i < NB) gcursor[i] = i * CAP;
}

__global__ __launch_bounds__(BIN_THREADS) void bin_edges(
    const int* __restrict__ src, const int* __restrict__ dst,
    const float* __restrict__ ew, const float* __restrict__ w_mp,
    int* __restrict__ gcursor, uint2* __restrict__ records)
{
    __shared__ int lhist[NB];
    __shared__ int lbase[NB];
    for (int i = threadIdx.x; i < NB; i += BIN_THREADS) lhist[i] = 0;
    __syncthreads();

    const float w = w_mp[0];
    const int base_e = blockIdx.x * BIN_CHUNK;
    int   bkt[BIN_EPT];
    uint2 rec[BIN_EPT];

    #pragma unroll
    for (int i = 0; i < BIN_EPT; ++i) {
        int e = base_e + threadIdx.x + i * BIN_THREADS;
        bkt[i] = -1;
        if (e < N_EDGES) {
            int d = dst[e];
            int b = d >> 6;
            bkt[i] = b;
            rec[i].x = __float_as_uint(w * ew[e]);
            rec[i].y = (unsigned)src[e] | ((unsigned)(d & 63) << 24);
            atomicAdd(&lhist[b], 1);
        }
    }
    __syncthreads();

    for (int i = threadIdx.x; i < NB; i += BIN_THREADS) {
        int c = lhist[i];
        lbase[i] = c ? atomicAdd(&gcursor[i], c) : 0;
        lhist[i] = 0;
    }
    __syncthreads();

    #pragma unroll
    for (int i = 0; i < BIN_EPT; ++i) {
        int b = bkt[i];
        if (b >= 0) {
            int pos = lbase[b] + atomicAdd(&lhist[b], 1);
            if (pos < (b + 1) * CAP)          // overflow guard (10-sigma margin)
                records[pos] = rec[i];
        }
    }
}

__global__ __launch_bounds__(AGG_THREADS) void sort_gather(
    const int*   __restrict__ gcursor,
    const uint2* __restrict__ records,
    const float* __restrict__ x,
    float*       __restrict__ out)
{
    __shared__ uint2 sorted[CAP];      // 10752 B
    __shared__ int   hist[NPB];
    __shared__ int   offs[NPB + 1];
    __shared__ int   cursor[NPB];

    const int b     = blockIdx.x;
    const int t     = threadIdx.x;
    const int rbase = b * CAP;
    const int cnt   = min(gcursor[b] - rbase, CAP);

    if (t < NPB) hist[t] = 0;
    __syncthreads();

    // load this bucket's records (coalesced) + LDS histogram by dst_low
    uint2 rec[RPT];
    #pragma unroll
    for (int i = 0; i < RPT; ++i) {
        int j = t + i * AGG_THREADS;
        rec[i].y = 0xFFFFFFFFu;            // "empty" marker
        if (j < cnt) {
            rec[i] = records[rbase + j];
            atomicAdd(&hist[rec[i].y >> 24], 1);
        }
    }
    __syncthreads();

    // wave 0: shuffle-scan the 64 counters -> exclusive offsets
    if (t < 64) {
        int v   = hist[t];
        int inc = v;
        #pragma unroll
        for (int d = 1; d < 64; d <<= 1) {
            int o = __shfl_up(inc, d, 64);
            if (t >= d) inc += o;
        }
        offs[t + 1] = inc;
        if (t == 0) offs[0] = 0;
        cursor[t] = inc - v;               // exclusive prefix
    }
    __syncthreads();

    // place into LDS in dst order
    #pragma unroll
    for (int i = 0; i < RPT; ++i) {
        if (rec[i].y != 0xFFFFFFFFu) {
            int dl   = rec[i].y >> 24;
            int slot = atomicAdd(&cursor[dl], 1);
            sorted[slot] = rec[i];
        }
    }
    __syncthreads();

    // gather: 8 threads per node, 4-way unrolled x-loads (4 in flight/thread)
    const int node  = t >> 3;
    const int q     = (t & 7) * 4;
    const int gnode = b * NPB + node;
    if (gnode >= N_NODES) return;

    int j  = offs[node];
    int je = offs[node + 1];
    float4 acc = make_float4(0.f, 0.f, 0.f, 0.f);

    for (; j + 4 <= je; j += 4) {
        uint2 r0 = sorted[j + 0];
        uint2 r1 = sorted[j + 1];
        uint2 r2 = sorted[j + 2];
        uint2 r3 = sorted[j + 3];
        const float4 v0 = *reinterpret_cast<const float4*>(
            x + (size_t)(r0.y & 0xFFFFFFu) * F_DIM + q);
        const float4 v1 = *reinterpret_cast<const float4*>(
            x + (size_t)(r1.y & 0xFFFFFFu) * F_DIM + q);
        const float4 v2 = *reinterpret_cast<const float4*>(
            x + (size_t)(r2.y & 0xFFFFFFu) * F_DIM + q);
        const float4 v3 = *reinterpret_cast<const float4*>(
            x + (size_t)(r3.y & 0xFFFFFFu) * F_DIM + q);
        float c0 = __uint_as_float(r0.x), c1 = __uint_as_float(r1.x);
        float c2 = __uint_as_float(r2.x), c3 = __uint_as_float(r3.x);
        acc.x += c0 * v0.x + c1 * v1.x + c2 * v2.x + c3 * v3.x;
        acc.y += c0 * v0.y + c1 * v1.y + c2 * v2.y + c3 * v3.y;
        acc.z += c0 * v0.z + c1 * v1.z + c2 * v2.z + c3 * v3.z;
        acc.w += c0 * v0.w + c1 * v1.w + c2 * v2.w + c3 * v3.w;
    }
    for (; j < je; ++j) {
        uint2 r = sorted[j];
        float c = __uint_as_float(r.x);
        const float4 v = *reinterpret_cast<const float4*>(
            x + (size_t)(r.y & 0xFFFFFFu) * F_DIM + q);
        acc.x += c * v.x;
        acc.y += c * v.y;
        acc.z += c * v.z;
        acc.w += c * v.w;
    }
    *reinterpret_cast<float4*>(out + (size_t)gnode * F_DIM + q) = acc;
}

// ---------------- fallback (R0): plain atomic scatter ----------------
__global__ __launch_bounds__(256) void gnn_scatter_atomic(
    const float* __restrict__ x, const int* __restrict__ src,
    const int* __restrict__ dst, const float* __restrict__ ew,
    const float* __restrict__ w_mp, float* __restrict__ out)
{
    const float w = w_mp[0];
    int gid = blockIdx.x * blockDim.x + threadIdx.x;
    int e = gid >> 3;
    int qq = (gid & 7) * 4;
    if (e >= N_EDGES) return;
    int s = src[e];
    int d = dst[e];
    float c = w * ew[e];
    const float4 xv = *reinterpret_cast<const float4*>(x + (size_t)s * F_DIM + qq);
    float* op = out + (size_t)d * F_DIM + qq;
    atomicAdd(op + 0, c * xv.x);
    atomicAdd(op + 1, c * xv.y);
    atomicAdd(op + 2, c * xv.z);
    atomicAdd(op + 3, c * xv.w);
}

extern "C" void kernel_launch(void* const* d_in, const int* in_sizes, int n_in,
                              void* d_out, int out_size, void* d_ws, size_t ws_size,
                              hipStream_t stream) {
    const float* x    = (const float*)d_in[0];
    const int*   ei   = (const int*)d_in[1];   // [2, E]: src row, then dst row
    const float* ew   = (const float*)d_in[2];
    const float* w_mp = (const float*)d_in[3];
    float* out = (float*)d_out;

    const int* src = ei;
    const int* dst = ei + N_EDGES;

    if (ws_size < WS_NEEDED) {
        hipMemsetAsync(d_out, 0, (size_t)out_size * sizeof(float), stream);
        int total = N_EDGES * 8;
        gnn_scatter_atomic<<<(total + 255) / 256, 256, 0, stream>>>(
            x, src, dst, ew, w_mp, out);
        return;
    }

    char* ws = (char*)d_ws;
    int*   gcursor = (int*)(ws + WS_CURSOR);
    uint2* records = (uint2*)(ws + WS_RECORDS);

    init_cursors<<<(NB + 255) / 256, 256, 0, stream>>>(gcursor);
    bin_edges<<<BIN_BLOCKS, BIN_THREADS, 0, stream>>>(src, dst, ew, w_mp,
                                                      gcursor, records);
    sort_gather<<<NB, AGG_THREADS, 0, stream>>>(gcursor, records, x, out);
    // sort_gather writes every out element -> no d_out memset needed
}